// Round 1
// baseline (77.198 us; speedup 1.0000x reference)
//
#include <hip/hip_runtime.h>
#include <hip/hip_bf16.h>
#include <math.h>

#define Bsz 16
#define Nn  500
#define Deg 32
#define Hd  128
#define Pg  100
#define Etot 16000   // Nn*Deg
#define CHUNKS 128
#define ROWS_PER_CHUNK 125  // Etot / CHUNKS

// ---------------- Kernel 0: transpose 4 weight matrices (H x H) ----------------
// slot 0 = Wq_last, 1 = Wq_visited, 2 = Wq, 3 = Wq_graph
__global__ void transpose_w(const float* __restrict__ wl, const float* __restrict__ wv,
                            const float* __restrict__ wq, const float* __restrict__ wg,
                            float* __restrict__ wt) {
    const float* src = (blockIdx.x == 0) ? wl : (blockIdx.x == 1) ? wv : (blockIdx.x == 2) ? wq : wg;
    float* dst = wt + (size_t)blockIdx.x * Hd * Hd;
    for (int i = threadIdx.x; i < Hd * Hd; i += blockDim.x) {
        int c = i >> 7, j = i & 127;
        dst[i] = src[j * Hd + c];   // dst[c*128+j] = src[j*128+c]
    }
}

// ---------------- Kernel 1: partial sums of embeddings over E ----------------
__global__ __launch_bounds__(256) void mean_partial(const float* __restrict__ emb,
                                                    float* __restrict__ partial) {
    int b = blockIdx.y, chunk = blockIdx.x;
    int tid = threadIdx.x;
    int rgrp = tid >> 5, c4 = tid & 31;          // 8 rows in flight, 32 float4 per row
    const float4* base = (const float4*)(emb + (size_t)b * Etot * Hd);
    int e0 = chunk * ROWS_PER_CHUNK;
    float4 acc = make_float4(0.f, 0.f, 0.f, 0.f);
    for (int e = e0 + rgrp; e < e0 + ROWS_PER_CHUNK; e += 8) {
        float4 v = base[(size_t)e * 32 + c4];
        acc.x += v.x; acc.y += v.y; acc.z += v.z; acc.w += v.w;
    }
    __shared__ float4 red[256];
    red[tid] = acc;
    __syncthreads();
    for (int s = 128; s >= 32; s >>= 1) {
        if (tid < s) {
            float4 a = red[tid], o = red[tid + s];
            a.x += o.x; a.y += o.y; a.z += o.z; a.w += o.w;
            red[tid] = a;
        }
        __syncthreads();
    }
    if (tid < 32) {
        ((float4*)partial)[((size_t)b * CHUNKS + chunk) * 32 + tid] = red[tid];
    }
}

// ---------------- Kernel 2: reduce partials -> mean -> q_graph = mean @ Wq_graph^T ----------------
__global__ __launch_bounds__(128) void mean_qgraph(const float* __restrict__ partial,
                                                   const float* __restrict__ wtg, // transposed Wq_graph
                                                   float* __restrict__ qg) {
    int b = blockIdx.x, j = threadIdx.x;
    float s = 0.f;
    for (int c = 0; c < CHUNKS; ++c)
        s += partial[((size_t)b * CHUNKS + c) * Hd + j];
    __shared__ float mean_s[Hd];
    mean_s[j] = s * (1.0f / (float)Etot);
    __syncthreads();
    float acc = 0.f;
#pragma unroll 8
    for (int c = 0; c < Hd; ++c)
        acc += mean_s[c] * wtg[c * Hd + j];
    qg[b * Hd + j] = acc;
}

// ---------------- Kernel 3: per-(b,p) z = Wk^T (Wq (q_last + q_first + q_graph + q_visited)) ----------------
__global__ __launch_bounds__(128) void compute_z(const float* __restrict__ q_first,
                                                 const float* __restrict__ visited,
                                                 const float* __restrict__ last_edge,
                                                 const float* __restrict__ qg,
                                                 const float* __restrict__ wt,  // [0]=Wq_last^T [1]=Wq_visited^T [2]=Wq^T
                                                 const float* __restrict__ wk,  // original Wk (row-major)
                                                 float* __restrict__ z_all) {
    int b = blockIdx.y, p = blockIdx.x, j = threadIdx.x;
    size_t row = ((size_t)b * Pg + p) * Hd;
    __shared__ float le_s[Hd], vv_s[Hd], fq_s[Hd], qh_s[Hd];
    float lev = last_edge[row + j];
    le_s[j] = lev;
    vv_s[j] = visited[row + j] + lev * (1.0f / (float)Nn);
    __syncthreads();
    const float* wtl = wt;
    const float* wtv = wt + Hd * Hd;
    const float* wtq = wt + 2 * Hd * Hd;
    float fq = q_first[row + j] + qg[b * Hd + j];
#pragma unroll 4
    for (int c = 0; c < Hd; ++c)
        fq += le_s[c] * wtl[c * Hd + j] + vv_s[c] * wtv[c * Hd + j];
    fq_s[j] = fq;
    __syncthreads();
    float qh = 0.f;
#pragma unroll 8
    for (int c = 0; c < Hd; ++c)
        qh += fq_s[c] * wtq[c * Hd + j];
    qh_s[j] = qh;
    __syncthreads();
    float z = 0.f;
#pragma unroll 8
    for (int c = 0; c < Hd; ++c)
        z += qh_s[c] * wk[c * Hd + j];   // z_t = sum_j qh_j * Wk[j, t] : coalesced
    z_all[row + j] = z;
}

// ---------------- Kernel 4: gather outgoing, scores, softmax, all outputs ----------------
__global__ __launch_bounds__(256) void decode(const float* __restrict__ emb,
                                              const float* __restrict__ dists,
                                              const float* __restrict__ pref,
                                              const int* __restrict__ indices,
                                              const int* __restrict__ lni_arr,
                                              const float* __restrict__ gmask,
                                              const float* __restrict__ z_all,
                                              float* __restrict__ out_probs,
                                              float* __restrict__ out_nk,
                                              float* __restrict__ out_og) {
    int b = blockIdx.y, p = blockIdx.x;
    int tid = threadIdx.x;
    int bp = b * Pg + p;
    int lni = lni_arr[bp];

    __shared__ float zs[Hd];
    __shared__ int nks[Deg];
    __shared__ float score_s[Deg];

    if (tid < Hd) zs[tid] = z_all[(size_t)bp * Hd + tid];
    if (tid < Deg) {
        int nk = indices[(((size_t)b * Etot) + (size_t)lni * Deg + tid) * 2 + 1];
        nks[tid] = nk;
        out_nk[(size_t)bp * Deg + tid] = (float)nk;
    }
    __syncthreads();

    const float4* ebase = (const float4*)(emb) + ((size_t)b * Etot + (size_t)lni * Deg) * 32;
    float4* obase = (float4*)(out_og) + (size_t)bp * Deg * 32;
    const float4* z4p = (const float4*)zs;

    int grp = tid >> 5, c4 = tid & 31;
    for (int r = grp; r < Deg; r += 8) {
        float4 v = ebase[r * 32 + c4];
        obase[r * 32 + c4] = v;
        float4 z4 = z4p[c4];
        float part = v.x * z4.x + v.y * z4.y + v.z * z4.z + v.w * z4.w;
        for (int m = 16; m >= 1; m >>= 1)
            part += __shfl_xor(part, m, 64);
        if (c4 == 0) score_s[r] = part;
    }
    __syncthreads();

    if (tid < Deg) {
        const float p0 = pref[0], p1 = pref[1];
        float s = score_s[tid] * 0.011048543456039805f;  // 1/(8*sqrt(128))
        int nk = nks[tid];
        float2 dd = *(const float2*)(dists + (((size_t)b * Nn + (size_t)lni) * Nn + nk) * 2);
        float ds = p0 * dd.x + p1 * dd.y;
        s -= ds * 0.7071067811865476f;                   // /sqrt(2)
        float sc = 10.0f * tanhf(s);
        float m = gmask[(size_t)bp * Nn + nk];
        if (isinf(m) && m < 0.f) m = -1.0e8f;
        float v = sc + m;
        float mx = v;
        for (int mm = 16; mm >= 1; mm >>= 1)
            mx = fmaxf(mx, __shfl_xor(mx, mm, 64));
        float e = expf(v - mx);
        float sum = e;
        for (int mm = 16; mm >= 1; mm >>= 1)
            sum += __shfl_xor(sum, mm, 64);
        out_probs[(size_t)bp * Deg + tid] = e / sum;
    }
}

extern "C" void kernel_launch(void* const* d_in, const int* in_sizes, int n_in,
                              void* d_out, int out_size, void* d_ws, size_t ws_size,
                              hipStream_t stream) {
    const float* emb       = (const float*)d_in[0];
    const float* dists     = (const float*)d_in[1];
    const float* pref      = (const float*)d_in[2];
    const int*   indices   = (const int*)d_in[3];
    // d_in[4] = Wq_first : unused by the reference
    const float* Wq_last    = (const float*)d_in[5];
    const float* Wq_visited = (const float*)d_in[6];
    const float* Wq_graph   = (const float*)d_in[7];
    const float* Wq         = (const float*)d_in[8];
    const float* Wk         = (const float*)d_in[9];
    const float* q_first    = (const float*)d_in[10];
    const float* visited    = (const float*)d_in[11];
    const float* last_edge  = (const float*)d_in[12];
    const int*   lni        = (const int*)d_in[13];
    const float* gmask      = (const float*)d_in[14];

    float* w = (float*)d_ws;
    float* ws_partial = w;                                    // 16*128*128 = 262144
    float* ws_qg      = ws_partial + (size_t)Bsz * CHUNKS * Hd; // 2048
    float* ws_z       = ws_qg + (size_t)Bsz * Hd;               // 204800
    float* ws_wt      = ws_z + (size_t)Bsz * Pg * Hd;           // 4*16384 = 65536

    float* out       = (float*)d_out;
    float* out_probs = out;                                   // B*P*Deg = 51200
    float* out_nk    = out + (size_t)Bsz * Pg * Deg;          // 51200
    float* out_og    = out + 2 * (size_t)Bsz * Pg * Deg;      // B*P*Deg*H

    transpose_w<<<4, 256, 0, stream>>>(Wq_last, Wq_visited, Wq, Wq_graph, ws_wt);
    mean_partial<<<dim3(CHUNKS, Bsz), 256, 0, stream>>>(emb, ws_partial);
    mean_qgraph<<<Bsz, Hd, 0, stream>>>(ws_partial, ws_wt + 3 * Hd * Hd, ws_qg);
    compute_z<<<dim3(Pg, Bsz), Hd, 0, stream>>>(q_first, visited, last_edge, ws_qg, ws_wt, Wk, ws_z);
    decode<<<dim3(Pg, Bsz), 256, 0, stream>>>(emb, dists, pref, indices, lni, gmask, ws_z,
                                              out_probs, out_nk, out_og);
}

// Round 2
// 66.439 us; speedup vs baseline: 1.1619x; 1.1619x over previous
//
#include <hip/hip_runtime.h>
#include <hip/hip_bf16.h>
#include <math.h>

#define Bsz 16
#define Nn  500
#define Deg 32
#define Hd  128
#define Pg  100
#define Etot 16000   // Nn*Deg
#define CHUNKS 64
#define ROWS_PER_CHUNK 250  // Etot / CHUNKS

// ============ K1: fused mean-partials (blocks 0..1023) + M^T prep (1024..1087) ============
// MT[s*128+r] = sum_t Wq[t*128+s] * Wk[t*128+r]   (= M[r,s], stored for coalesced r-reads)
__global__ __launch_bounds__(256) void fused_a(const float* __restrict__ emb,
                                               const float* __restrict__ wq,
                                               const float* __restrict__ wk,
                                               float* __restrict__ partial,
                                               float* __restrict__ mt) {
    int blk = blockIdx.x;
    int tid = threadIdx.x;
    __shared__ float4 red[256];
    if (blk < Bsz * CHUNKS) {
        int b = blk >> 6, chunk = blk & 63;
        int rgrp = tid >> 5, c4 = tid & 31;
        const float4* base = (const float4*)(emb + (size_t)b * Etot * Hd);
        int e0 = chunk * ROWS_PER_CHUNK;
        float4 acc = make_float4(0.f, 0.f, 0.f, 0.f);
        for (int e = e0 + rgrp; e < e0 + ROWS_PER_CHUNK; e += 8) {
            float4 v = base[(size_t)e * 32 + c4];
            acc.x += v.x; acc.y += v.y; acc.z += v.z; acc.w += v.w;
        }
        red[tid] = acc;
        __syncthreads();
        for (int s = 128; s >= 32; s >>= 1) {
            if (tid < s) {
                float4 a = red[tid], o = red[tid + s];
                a.x += o.x; a.y += o.y; a.z += o.z; a.w += o.w;
                red[tid] = a;
            }
            __syncthreads();
        }
        if (tid < 32)
            ((float4*)partial)[((size_t)b * CHUNKS + chunk) * 32 + tid] = red[tid];
    } else {
        int s = ((blk - Bsz * CHUNKS) << 1) | (tid >> 7);
        int r = tid & 127;
        float acc = 0.f;
#pragma unroll 8
        for (int t = 0; t < Hd; ++t)
            acc += wq[t * Hd + s] * wk[t * Hd + r];
        mt[s * Hd + r] = acc;
    }
}

// ============ K2: AT/BT/GT from MT ============
// f=0: AT[u*128+r] = sum_s (WqL[s,u] + WqV[s,u]/500) * MT[s*128+r]   (applied to last_edge)
// f=1: BT[u*128+r] = sum_s  WqV[s,u]                 * MT[s*128+r]   (applied to visited)
// f=2: GT[c*128+r] = sum_s  WqG[s,c]                 * MT[s*128+r]   (applied to mean)
__global__ __launch_bounds__(256) void prep2(const float* __restrict__ wql,
                                             const float* __restrict__ wqv,
                                             const float* __restrict__ wqg,
                                             const float* __restrict__ mt,
                                             float* __restrict__ at,
                                             float* __restrict__ bt,
                                             float* __restrict__ gt) {
    int blk = blockIdx.x;
    int f = blk >> 6;
    int u = ((blk & 63) << 1) | (threadIdx.x >> 7);
    int r = threadIdx.x & 127;
    float acc = 0.f;
    if (f == 0) {
#pragma unroll 8
        for (int s = 0; s < Hd; ++s)
            acc += (wql[s * Hd + u] + wqv[s * Hd + u] * (1.f / (float)Nn)) * mt[s * Hd + r];
        at[u * Hd + r] = acc;
    } else if (f == 1) {
#pragma unroll 8
        for (int s = 0; s < Hd; ++s)
            acc += wqv[s * Hd + u] * mt[s * Hd + r];
        bt[u * Hd + r] = acc;
    } else {
#pragma unroll 8
        for (int s = 0; s < Hd; ++s)
            acc += wqg[s * Hd + u] * mt[s * Hd + r];
        gt[u * Hd + r] = acc;
    }
}

// ============ K3: per-b mean reduce + gz + Z GEMM ============
// z[bp,r] = sum_u AT[u,r]*le[bp,u] + sum_u BT[u,r]*vis[bp,u] + sum_s MT[s,r]*qf[bp,s] + gz[b,r]
// grid: 16 b x 13 pblk; 8 rows per block (last block 4)
__global__ __launch_bounds__(256) void zgemm_gz(const float* __restrict__ partial,
                                                const float* __restrict__ gt,
                                                const float* __restrict__ at,
                                                const float* __restrict__ bt,
                                                const float* __restrict__ mt,
                                                const float* __restrict__ qf,
                                                const float* __restrict__ vis,
                                                const float* __restrict__ le,
                                                float* __restrict__ z) {
    int b = blockIdx.x / 13, pblk = blockIdx.x % 13;
    int p0 = pblk * 8, nrows = (pblk == 12) ? 4 : 8;
    int tid = threadIdx.x;
    __shared__ __align__(16) float mean_s[Hd];
    __shared__ __align__(16) float gz_s[Hd];
    __shared__ float ps[2][Hd];
    __shared__ float4 in_s[3][8][32];   // [arr][row][c4]  arr: 0=le 1=vis 2=qf

    // A1: reduce partials for this b
    {
        int c = tid & 127, h = tid >> 7;
        float s = 0.f;
        const float* pb = partial + (size_t)b * CHUNKS * Hd;
        for (int k = h * 32; k < h * 32 + 32; ++k)
            s += pb[k * Hd + c];
        ps[h][c] = s;
    }
    __syncthreads();
    if (tid < Hd)
        mean_s[tid] = (ps[0][tid] + ps[1][tid]) * (1.f / (float)Etot);
    __syncthreads();
    // A2: waves 0-1 compute gz; waves 2-3 stage the 3 input tiles
    if (tid < Hd) {
        float g = 0.f;
#pragma unroll 8
        for (int c = 0; c < Hd; ++c)
            g += mean_s[c] * gt[c * Hd + tid];
        gz_s[tid] = g;
    } else {
        int t2 = tid - 128;
        size_t base4 = ((size_t)b * Pg + p0) * 32;   // float4 index
        const float4* le4 = (const float4*)le + base4;
        const float4* vi4 = (const float4*)vis + base4;
        const float4* qf4 = (const float4*)qf + base4;
        int tot = nrows * 32;
        for (int i = t2; i < tot; i += 128) {
            int rr = i >> 5, c4 = i & 31;
            in_s[0][rr][c4] = le4[i];
            in_s[1][rr][c4] = vi4[i];
            in_s[2][rr][c4] = qf4[i];
        }
    }
    __syncthreads();
    // B: thread = 1 row x 4 cols
    int tg = tid & 31, rg = tid >> 5;
    if (rg < nrows) {
        float4 acc = ((const float4*)gz_s)[tg];
        const float4* at4 = (const float4*)at;
        const float4* bt4 = (const float4*)bt;
        const float4* mt4 = (const float4*)mt;
        for (int c4 = 0; c4 < 32; ++c4) {
            float4 lv = in_s[0][rg][c4];
            float4 vv = in_s[1][rg][c4];
            float4 qv = in_s[2][rg][c4];
            int cb = c4 * 4;
#pragma unroll
            for (int j = 0; j < 4; ++j) {
                float4 wa = at4[(cb + j) * 32 + tg];
                float4 wb = bt4[(cb + j) * 32 + tg];
                float4 wm = mt4[(cb + j) * 32 + tg];
                float lj = j == 0 ? lv.x : j == 1 ? lv.y : j == 2 ? lv.z : lv.w;
                float vj = j == 0 ? vv.x : j == 1 ? vv.y : j == 2 ? vv.z : vv.w;
                float qj = j == 0 ? qv.x : j == 1 ? qv.y : j == 2 ? qv.z : qv.w;
                acc.x += lj * wa.x + vj * wb.x + qj * wm.x;
                acc.y += lj * wa.y + vj * wb.y + qj * wm.y;
                acc.z += lj * wa.z + vj * wb.z + qj * wm.z;
                acc.w += lj * wa.w + vj * wb.w + qj * wm.w;
            }
        }
        ((float4*)(z + ((size_t)b * Pg + p0 + rg) * Hd))[tg] = acc;
    }
}

// ============ K4: gather outgoing, scores, softmax, all outputs (proven in R1) ============
__global__ __launch_bounds__(256) void decode(const float* __restrict__ emb,
                                              const float* __restrict__ dists,
                                              const float* __restrict__ pref,
                                              const int* __restrict__ indices,
                                              const int* __restrict__ lni_arr,
                                              const float* __restrict__ gmask,
                                              const float* __restrict__ z_all,
                                              float* __restrict__ out_probs,
                                              float* __restrict__ out_nk,
                                              float* __restrict__ out_og) {
    int b = blockIdx.y, p = blockIdx.x;
    int tid = threadIdx.x;
    int bp = b * Pg + p;
    int lni = lni_arr[bp];

    __shared__ __align__(16) float zs[Hd];
    __shared__ int nks[Deg];
    __shared__ float score_s[Deg];

    if (tid < Hd) zs[tid] = z_all[(size_t)bp * Hd + tid];
    if (tid < Deg) {
        int nk = indices[(((size_t)b * Etot) + (size_t)lni * Deg + tid) * 2 + 1];
        nks[tid] = nk;
        out_nk[(size_t)bp * Deg + tid] = (float)nk;
    }
    __syncthreads();

    const float4* ebase = (const float4*)(emb) + ((size_t)b * Etot + (size_t)lni * Deg) * 32;
    float4* obase = (float4*)(out_og) + (size_t)bp * Deg * 32;
    const float4* z4p = (const float4*)zs;

    int grp = tid >> 5, c4 = tid & 31;
    for (int r = grp; r < Deg; r += 8) {
        float4 v = ebase[r * 32 + c4];
        obase[r * 32 + c4] = v;
        float4 z4 = z4p[c4];
        float part = v.x * z4.x + v.y * z4.y + v.z * z4.z + v.w * z4.w;
        for (int m = 16; m >= 1; m >>= 1)
            part += __shfl_xor(part, m, 64);
        if (c4 == 0) score_s[r] = part;
    }
    __syncthreads();

    if (tid < Deg) {
        const float p0 = pref[0], p1 = pref[1];
        float s = score_s[tid] * 0.011048543456039805f;  // 1/(8*sqrt(128))
        int nk = nks[tid];
        float2 dd = *(const float2*)(dists + (((size_t)b * Nn + (size_t)lni) * Nn + nk) * 2);
        float ds = p0 * dd.x + p1 * dd.y;
        s -= ds * 0.7071067811865476f;                   // /sqrt(2)
        float sc = 10.0f * tanhf(s);
        float m = gmask[(size_t)bp * Nn + nk];
        if (isinf(m) && m < 0.f) m = -1.0e8f;
        float v = sc + m;
        float mx = v;
        for (int mm = 16; mm >= 1; mm >>= 1)
            mx = fmaxf(mx, __shfl_xor(mx, mm, 64));
        float e = expf(v - mx);
        float sum = e;
        for (int mm = 16; mm >= 1; mm >>= 1)
            sum += __shfl_xor(sum, mm, 64);
        out_probs[(size_t)bp * Deg + tid] = e / sum;
    }
}

extern "C" void kernel_launch(void* const* d_in, const int* in_sizes, int n_in,
                              void* d_out, int out_size, void* d_ws, size_t ws_size,
                              hipStream_t stream) {
    const float* emb       = (const float*)d_in[0];
    const float* dists     = (const float*)d_in[1];
    const float* pref      = (const float*)d_in[2];
    const int*   indices   = (const int*)d_in[3];
    // d_in[4] = Wq_first : unused by the reference
    const float* Wq_last    = (const float*)d_in[5];
    const float* Wq_visited = (const float*)d_in[6];
    const float* Wq_graph   = (const float*)d_in[7];
    const float* Wq         = (const float*)d_in[8];
    const float* Wk         = (const float*)d_in[9];
    const float* q_first    = (const float*)d_in[10];
    const float* visited    = (const float*)d_in[11];
    const float* last_edge  = (const float*)d_in[12];
    const int*   lni        = (const int*)d_in[13];
    const float* gmask      = (const float*)d_in[14];

    float* w = (float*)d_ws;
    float* ws_partial = w;                                       // 16*64*128 = 131072
    float* ws_mt      = ws_partial + (size_t)Bsz * CHUNKS * Hd;  // 16384
    float* ws_at      = ws_mt + Hd * Hd;                         // 16384
    float* ws_bt      = ws_at + Hd * Hd;                         // 16384
    float* ws_gt      = ws_bt + Hd * Hd;                         // 16384
    float* ws_z       = ws_gt + Hd * Hd;                         // 204800

    float* out       = (float*)d_out;
    float* out_probs = out;                                      // B*P*Deg
    float* out_nk    = out + (size_t)Bsz * Pg * Deg;
    float* out_og    = out + 2 * (size_t)Bsz * Pg * Deg;

    fused_a<<<Bsz * CHUNKS + 64, 256, 0, stream>>>(emb, Wq, Wk, ws_partial, ws_mt);
    prep2<<<192, 256, 0, stream>>>(Wq_last, Wq_visited, Wq_graph, ws_mt, ws_at, ws_bt, ws_gt);
    zgemm_gz<<<Bsz * 13, 256, 0, stream>>>(ws_partial, ws_gt, ws_at, ws_bt, ws_mt,
                                           q_first, visited, last_edge, ws_z);
    decode<<<dim3(Pg, Bsz), 256, 0, stream>>>(emb, dists, pref, indices, lni, gmask, ws_z,
                                              out_probs, out_nk, out_og);
}

// Round 3
// 60.612 us; speedup vs baseline: 1.2736x; 1.0961x over previous
//
#include <hip/hip_runtime.h>
#include <hip/hip_bf16.h>
#include <math.h>

#define Bsz 16
#define Nn  500
#define Deg 32
#define Hd  128
#define Pg  100
#define Etot 16000   // Nn*Deg
#define CHUNKS 64
#define ROWS_PER_CHUNK 250  // Etot / CHUNKS
#define PREP_BLKS 256       // 64 MT + 64 AT + 64 BT + 64 GT

// ============ K1: all weight prep (blocks 0..255) + mean partials (256..1279) ============
// MT[s*128+r] = sum_t Wq[t,s]*Wk[t,r]
// AT[u*128+r] = sum_t (sum_s CombL[s,u]*Wq[t,s]) * Wk[t,r],  CombL = WqL + WqV/500
// BT[u*128+r] = same with WqV ;  GT[c*128+r] = same with WqG
__global__ __launch_bounds__(256) void fused_all(const float* __restrict__ emb,
                                                 const float* __restrict__ wq,
                                                 const float* __restrict__ wk,
                                                 const float* __restrict__ wql,
                                                 const float* __restrict__ wqv,
                                                 const float* __restrict__ wqg,
                                                 float* __restrict__ partial,
                                                 float* __restrict__ mt,
                                                 float* __restrict__ at,
                                                 float* __restrict__ bt,
                                                 float* __restrict__ gt) {
    int blk = blockIdx.x;
    int tid = threadIdx.x;
    __shared__ float4 red[256];
    __shared__ float wv_s[2][Hd];

    if (blk >= PREP_BLKS) {
        // ---- mean partials ----
        int mb = blk - PREP_BLKS;
        int b = mb >> 6, chunk = mb & 63;
        int rgrp = tid >> 5, c4 = tid & 31;
        const float4* base = (const float4*)(emb + (size_t)b * Etot * Hd);
        int e0 = chunk * ROWS_PER_CHUNK;
        float4 acc = make_float4(0.f, 0.f, 0.f, 0.f);
        for (int e = e0 + rgrp; e < e0 + ROWS_PER_CHUNK; e += 8) {
            float4 v = base[(size_t)e * 32 + c4];
            acc.x += v.x; acc.y += v.y; acc.z += v.z; acc.w += v.w;
        }
        red[tid] = acc;
        __syncthreads();
        for (int s = 128; s >= 32; s >>= 1) {
            if (tid < s) {
                float4 a = red[tid], o = red[tid + s];
                a.x += o.x; a.y += o.y; a.z += o.z; a.w += o.w;
                red[tid] = a;
            }
            __syncthreads();
        }
        if (tid < 32)
            ((float4*)partial)[((size_t)b * CHUNKS + chunk) * 32 + tid] = red[tid];
        return;
    }

    int h = tid >> 7;         // 0/1 : which output row of this block
    int r = tid & 127;
    if (blk < 64) {
        // ---- MT ----
        int s = (blk << 1) | h;
        float acc = 0.f;
#pragma unroll 8
        for (int t = 0; t < Hd; ++t)
            acc += wq[t * Hd + s] * wk[t * Hd + r];
        mt[s * Hd + r] = acc;
        return;
    }
    // ---- AT / BT / GT : two-stage ----
    int f = (blk - 64) >> 6;                 // 0=AT 1=BT 2=GT
    int u = (((blk - 64) & 63) << 1) | h;
    int t = r;                               // stage-1: this thread's t index
    float acc1 = 0.f;
    if (f == 0) {
#pragma unroll 8
        for (int s = 0; s < Hd; ++s)
            acc1 += (wql[s * Hd + u] + wqv[s * Hd + u] * (1.f / (float)Nn)) * wq[t * Hd + s];
    } else if (f == 1) {
#pragma unroll 8
        for (int s = 0; s < Hd; ++s)
            acc1 += wqv[s * Hd + u] * wq[t * Hd + s];
    } else {
#pragma unroll 8
        for (int s = 0; s < Hd; ++s)
            acc1 += wqg[s * Hd + u] * wq[t * Hd + s];
    }
    wv_s[h][t] = acc1;
    __syncthreads();
    float acc = 0.f;
#pragma unroll 8
    for (int tt = 0; tt < Hd; ++tt)
        acc += wv_s[h][tt] * wk[tt * Hd + r];
    float* dst = (f == 0) ? at : (f == 1) ? bt : gt;
    dst[u * Hd + r] = acc;
}

// ============ K2: per-b mean reduce + gz + Z GEMM (proven R2) ============
__global__ __launch_bounds__(256) void zgemm_gz(const float* __restrict__ partial,
                                                const float* __restrict__ gt,
                                                const float* __restrict__ at,
                                                const float* __restrict__ bt,
                                                const float* __restrict__ mt,
                                                const float* __restrict__ qf,
                                                const float* __restrict__ vis,
                                                const float* __restrict__ le,
                                                float* __restrict__ z) {
    int b = blockIdx.x / 13, pblk = blockIdx.x % 13;
    int p0 = pblk * 8, nrows = (pblk == 12) ? 4 : 8;
    int tid = threadIdx.x;
    __shared__ __align__(16) float mean_s[Hd];
    __shared__ __align__(16) float gz_s[Hd];
    __shared__ float ps[2][Hd];
    __shared__ float4 in_s[3][8][32];

    {
        int c = tid & 127, h = tid >> 7;
        float s = 0.f;
        const float* pb = partial + (size_t)b * CHUNKS * Hd;
        for (int k = h * 32; k < h * 32 + 32; ++k)
            s += pb[k * Hd + c];
        ps[h][c] = s;
    }
    __syncthreads();
    if (tid < Hd)
        mean_s[tid] = (ps[0][tid] + ps[1][tid]) * (1.f / (float)Etot);
    __syncthreads();
    if (tid < Hd) {
        float g = 0.f;
#pragma unroll 8
        for (int c = 0; c < Hd; ++c)
            g += mean_s[c] * gt[c * Hd + tid];
        gz_s[tid] = g;
    } else {
        int t2 = tid - 128;
        size_t base4 = ((size_t)b * Pg + p0) * 32;
        const float4* le4 = (const float4*)le + base4;
        const float4* vi4 = (const float4*)vis + base4;
        const float4* qf4 = (const float4*)qf + base4;
        int tot = nrows * 32;
        for (int i = t2; i < tot; i += 128) {
            int rr = i >> 5, c4 = i & 31;
            in_s[0][rr][c4] = le4[i];
            in_s[1][rr][c4] = vi4[i];
            in_s[2][rr][c4] = qf4[i];
        }
    }
    __syncthreads();
    int tg = tid & 31, rg = tid >> 5;
    if (rg < nrows) {
        float4 acc = ((const float4*)gz_s)[tg];
        const float4* at4 = (const float4*)at;
        const float4* bt4 = (const float4*)bt;
        const float4* mt4 = (const float4*)mt;
        for (int c4 = 0; c4 < 32; ++c4) {
            float4 lv = in_s[0][rg][c4];
            float4 vv = in_s[1][rg][c4];
            float4 qv = in_s[2][rg][c4];
            int cb = c4 * 4;
#pragma unroll
            for (int j = 0; j < 4; ++j) {
                float4 wa = at4[(cb + j) * 32 + tg];
                float4 wb = bt4[(cb + j) * 32 + tg];
                float4 wm = mt4[(cb + j) * 32 + tg];
                float lj = j == 0 ? lv.x : j == 1 ? lv.y : j == 2 ? lv.z : lv.w;
                float vj = j == 0 ? vv.x : j == 1 ? vv.y : j == 2 ? vv.z : vv.w;
                float qj = j == 0 ? qv.x : j == 1 ? qv.y : j == 2 ? qv.z : qv.w;
                acc.x += lj * wa.x + vj * wb.x + qj * wm.x;
                acc.y += lj * wa.y + vj * wb.y + qj * wm.y;
                acc.z += lj * wa.z + vj * wb.z + qj * wm.z;
                acc.w += lj * wa.w + vj * wb.w + qj * wm.w;
            }
        }
        ((float4*)(z + ((size_t)b * Pg + p0 + rg) * Hd))[tg] = acc;
    }
}

// ============ K3: decode — scattered loads prefetched into regs before the gather ============
__global__ __launch_bounds__(256) void decode(const float* __restrict__ emb,
                                              const float* __restrict__ dists,
                                              const float* __restrict__ pref,
                                              const int* __restrict__ indices,
                                              const int* __restrict__ lni_arr,
                                              const float* __restrict__ gmask,
                                              const float* __restrict__ z_all,
                                              float* __restrict__ out_probs,
                                              float* __restrict__ out_nk,
                                              float* __restrict__ out_og) {
    int b = blockIdx.y, p = blockIdx.x;
    int tid = threadIdx.x;
    int bp = b * Pg + p;
    int lni = lni_arr[bp];

    __shared__ __align__(16) float zs[Hd];
    __shared__ float score_s[Deg];

    // Prefetch all scattered small loads into registers; they fly under the gather loop.
    int nk = 0; float2 dd = make_float2(0.f, 0.f); float mval = 0.f;
    float p0v = 0.f, p1v = 0.f;
    if (tid < Deg) {
        nk = indices[(((size_t)b * Etot) + (size_t)lni * Deg + tid) * 2 + 1];
        out_nk[(size_t)bp * Deg + tid] = (float)nk;
        dd = *(const float2*)(dists + (((size_t)b * Nn + (size_t)lni) * Nn + nk) * 2);
        mval = gmask[(size_t)bp * Nn + nk];
        p0v = pref[0]; p1v = pref[1];
    }
    if (tid < Hd) zs[tid] = z_all[(size_t)bp * Hd + tid];
    __syncthreads();

    const float4* ebase = (const float4*)(emb) + ((size_t)b * Etot + (size_t)lni * Deg) * 32;
    float4* obase = (float4*)(out_og) + (size_t)bp * Deg * 32;
    const float4* z4p = (const float4*)zs;

    int grp = tid >> 5, c4 = tid & 31;
    float4 z4 = z4p[c4];
    for (int r = grp; r < Deg; r += 8) {
        float4 v = ebase[r * 32 + c4];
        obase[r * 32 + c4] = v;
        float part = v.x * z4.x + v.y * z4.y + v.z * z4.z + v.w * z4.w;
        for (int m = 16; m >= 1; m >>= 1)
            part += __shfl_xor(part, m, 64);
        if (c4 == 0) score_s[r] = part;
    }
    __syncthreads();

    if (tid < Deg) {
        float s = score_s[tid] * 0.011048543456039805f;  // 1/(8*sqrt(128))
        float ds = p0v * dd.x + p1v * dd.y;
        s -= ds * 0.7071067811865476f;                   // /sqrt(2)
        float sc = 10.0f * tanhf(s);
        float m = mval;
        if (isinf(m) && m < 0.f) m = -1.0e8f;
        float v = sc + m;
        float mx = v;
        for (int mm = 16; mm >= 1; mm >>= 1)
            mx = fmaxf(mx, __shfl_xor(mx, mm, 64));
        float e = expf(v - mx);
        float sum = e;
        for (int mm = 16; mm >= 1; mm >>= 1)
            sum += __shfl_xor(sum, mm, 64);
        out_probs[(size_t)bp * Deg + tid] = e / sum;
    }
}

extern "C" void kernel_launch(void* const* d_in, const int* in_sizes, int n_in,
                              void* d_out, int out_size, void* d_ws, size_t ws_size,
                              hipStream_t stream) {
    const float* emb       = (const float*)d_in[0];
    const float* dists     = (const float*)d_in[1];
    const float* pref      = (const float*)d_in[2];
    const int*   indices   = (const int*)d_in[3];
    // d_in[4] = Wq_first : unused by the reference
    const float* Wq_last    = (const float*)d_in[5];
    const float* Wq_visited = (const float*)d_in[6];
    const float* Wq_graph   = (const float*)d_in[7];
    const float* Wq         = (const float*)d_in[8];
    const float* Wk         = (const float*)d_in[9];
    const float* q_first    = (const float*)d_in[10];
    const float* visited    = (const float*)d_in[11];
    const float* last_edge  = (const float*)d_in[12];
    const int*   lni        = (const int*)d_in[13];
    const float* gmask      = (const float*)d_in[14];

    float* w = (float*)d_ws;
    float* ws_partial = w;                                       // 16*64*128
    float* ws_mt      = ws_partial + (size_t)Bsz * CHUNKS * Hd;
    float* ws_at      = ws_mt + Hd * Hd;
    float* ws_bt      = ws_at + Hd * Hd;
    float* ws_gt      = ws_bt + Hd * Hd;
    float* ws_z       = ws_gt + Hd * Hd;

    float* out       = (float*)d_out;
    float* out_probs = out;
    float* out_nk    = out + (size_t)Bsz * Pg * Deg;
    float* out_og    = out + 2 * (size_t)Bsz * Pg * Deg;

    fused_all<<<PREP_BLKS + Bsz * CHUNKS, 256, 0, stream>>>(emb, Wq, Wk, Wq_last, Wq_visited,
                                                            Wq_graph, ws_partial, ws_mt,
                                                            ws_at, ws_bt, ws_gt);
    zgemm_gz<<<Bsz * 13, 256, 0, stream>>>(ws_partial, ws_gt, ws_at, ws_bt, ws_mt,
                                           q_first, visited, last_edge, ws_z);
    decode<<<dim3(Pg, Bsz), 256, 0, stream>>>(emb, dists, pref, indices, lni, gmask, ws_z,
                                              out_probs, out_nk, out_og);
}